// Round 8
// baseline (650.448 us; speedup 1.0000x reference)
//
#include <hip/hip_runtime.h>
#include <hip/hip_bf16.h>

// Problem constants
#define NT   1000
#define NS   2048
#define NH   16
#define NR   8
#define HS   256
#define TOUT 993   // NT - NR + 1

typedef __attribute__((ext_vector_type(8))) short short8;
typedef __attribute__((ext_vector_type(4))) float f32x4;

__device__ __forceinline__ ushort f2bf(float f) {
    union { float f; unsigned int u; } v; v.f = f;
    unsigned int u = v.u;
    return (ushort)((u + 0x7fffu + ((u >> 16) & 1u)) >> 16);
}
__device__ __forceinline__ float bf2f(ushort u) {
    union { unsigned int i; float f; } v; v.i = ((unsigned int)u) << 16; return v.f;
}
__device__ __forceinline__ unsigned int packbf2(float lo, float hi) {
    union { __hip_bfloat162 b; unsigned int u; } v;
    v.b = __float22bfloat162_rn(make_float2(lo, hi));
    return v.u;
}
__device__ __forceinline__ float sigf(float x) { return 1.f / (1.f + __expf(-x)); }
// tanh via single exp2: tanh(z) = 1 - 2/(exp2(z*2*log2e)+1)
__device__ __forceinline__ float fast_tanh(float z) {
    float e = exp2f(z * 2.885390082f);
    return 1.f - 2.f * __builtin_amdgcn_rcpf(e + 1.f);
}
// paired fma on float2 halves
__device__ __forceinline__ float2 f2fma(float s, float2 w, float2 acc) {
    return make_float2(fmaf(s, w.x, acc.x), fmaf(s, w.y, acc.y));
}
// DPP 16-lane-row reduction step: v += v[dpp-peer]
template<int CTRL>
__device__ __forceinline__ float dpp_add(float v) {
    int s = __builtin_amdgcn_update_dpp(0, __builtin_bit_cast(int, v), CTRL, 0xf, 0xf, true);
    return v + __builtin_bit_cast(float, s);
}

// ---------------- Kernel A: per-site setup (fp32 inputs) ----------------
__global__ __launch_bounds__(256) void kA(
    const float* __restrict__ xc, const float* __restrict__ W_fc, const float* __restrict__ b_fc,
    const float* __restrict__ W_r, const float* __restrict__ b_r,
    const float* __restrict__ W_g, const float* __restrict__ b_g,
    const float* __restrict__ b_kin, const float* __restrict__ W_kout,
    float* __restrict__ stateK, float* __restrict__ params, ushort* __restrict__ Wt_g)
{
    __shared__ float xcs[32];
    __shared__ float hG[256];
    __shared__ float pGR[288];
    const int s = blockIdx.x, tid = threadIdx.x;

    if (tid < 32) xcs[tid] = xc[s * 32 + tid];
    __syncthreads();

    float acc = b_fc[tid];
#pragma unroll 8
    for (int k = 0; k < 32; ++k) acc = fmaf(xcs[k], W_fc[k * 256 + tid], acc);
    stateK[s * 256 + tid] = acc + b_kin[tid];
    hG[tid] = tanhf(acc);
    __syncthreads();

    for (int j = tid; j < 288; j += 256) {
        const float* W = (j < 144) ? W_g : W_r;
        const float* b = (j < 144) ? b_g : b_r;
        int col = (j < 144) ? j : (j - 144);
        float a = b[col];
#pragma unroll 4
        for (int k = 0; k < 256; ++k) a = fmaf(hG[k], W[k * 144 + col], a);
        pGR[j] = a;
    }
    __syncthreads();

    if (tid < 16) {
        const int h = tid;
        float g0 = pGR[h],       g1 = pGR[16 + h],  g2 = pGR[32 + h];
        float g3 = pGR[48 + h],  g4 = pGR[64 + h],  g5 = pGR[80 + h];
        float g6 = pGR[96 + h],  g7 = pGR[112 + h], g8 = pGR[128 + h];
        float kp = sigf(g0), ksg = sigf(g1), kd = sigf(g2), gd = sigf(g3);
        float t4 = sigf(g4) * 10.f; float gl = t4 * t4 * t4;
        float qb = fmaxf(g5, 0.f) * 0.1f;
        float gi = fminf(fmaxf(g7 * (1.f / 6.f) + 0.5f, 0.f), 1.f) * 0.5f;
        float ge = fmaxf(g8, 0.f);
        float m = g6;
        for (int o = 1; o < 16; o <<= 1) m = fmaxf(m, __shfl_xor(m, o));
        float e = __expf(g6 - m), esum = e;
        for (int o = 1; o < 16; o <<= 1) esum += __shfl_xor(esum, o);
        float ga = e / esum;
        float r[9], rm = -1e30f;
#pragma unroll
        for (int i = 0; i < 9; ++i) { r[i] = pGR[144 + h * 9 + i]; rm = fmaxf(rm, r[i]); }
        float er[9], es = 0.f;
#pragma unroll
        for (int i = 0; i < 9; ++i) { er[i] = __expf(r[i] - rm); es += er[i]; }
        float inv_es = 1.f / es, c = 0.f, wsum = 0.f, w[8];
#pragma unroll
        for (int i = 0; i < 8; ++i) {
            float si = er[i] * inv_es; c += si;
            float wi = fminf(c, 1.f - c + si);
            w[i] = wi; wsum += wi;
        }
        const int base = s * 16 + h;
        params[0 * 32768 + base] = kp;  params[1 * 32768 + base] = ksg;
        params[2 * 32768 + base] = kd;  params[3 * 32768 + base] = gd;
        params[4 * 32768 + base] = gl;  params[5 * 32768 + base] = qb;
        params[6 * 32768 + base] = gi;  params[7 * 32768 + base] = ge;
        float sc = ga / wsum;
#pragma unroll
        for (int i = 0; i < 8; ++i) params[(8 + i) * 32768 + base] = w[i] * sc;
    }

    if (s == 0) {
        for (int i = tid; i < 48 * 256; i += 256) {
            int k = i / 48, col = i - k * 48;
            Wt_g[col * 264 + k] = f2bf(W_kout[i]);   // transpose to bf16, stride 264
        }
    }
}

// ---------------- Kernel B v6 (unchanged from R7): LDS staging, 5-t batch ----------------
__global__ __launch_bounds__(256, 3) void kB(
    const float* __restrict__ x,
    const float* __restrict__ stateK, const float* __restrict__ W_kin, const float* __restrict__ b_kout,
    const ushort* __restrict__ Wt_g,
    unsigned int* __restrict__ kmki, ushort* __restrict__ keA)
{
    __shared__ ushort Wt[48 * 264];    // 25,344 B
    __shared__ float  stS[16 * 260];   // 16,640 B
    __shared__ float  wkS[1024];       //  4,096 B
    const int tid = threadIdx.x;
    const int st = blockIdx.x & 127;   // site tile (0..127)
    const int tg = blockIdx.x >> 7;    // t group (0..49)
    const int s0 = st << 4;

    for (int i = tid; i < 3168; i += 256)
        ((uint2*)Wt)[i] = ((const uint2*)Wt_g)[i];
#pragma unroll
    for (int i = tid; i < 1024; i += 256) {
        int row = i >> 6, c = (i & 63) << 2;
        *(float4*)(stS + row * 260 + c) = *(const float4*)(stateK + (s0 + row) * 256 + c);
    }
    *(float4*)(wkS + tid * 4) = ((const float4*)W_kin)[tid];
    __syncthreads();

    const int wv = tid >> 6, lane = tid & 63;
    const int mi = lane & 15, quad = lane >> 4;
    const int site = s0 + mi;
    const int t0 = tg * 20 + wv * 5;   // 50*20 = 1000, guard-free

    float xf[5][4];
#pragma unroll
    for (int ti = 0; ti < 5; ++ti) {
        const int xb = ((t0 + ti) * 2048 + site) * 6;
        float2 u23 = *(const float2*)(x + xb + 2);
        float2 u45 = *(const float2*)(x + xb + 4);
        xf[ti][0] = u23.x; xf[ti][1] = u23.y; xf[ti][2] = u45.x; xf[ti][3] = u45.y;
    }

    const float* stp = stS + mi * 260 + quad * 8;
    const float* wkp = wkS + quad * 8;
    const ushort* Wt0 = Wt + mi * 264 + quad * 8;

    f32x4 acc[5][3];
#pragma unroll
    for (int ti = 0; ti < 5; ++ti)
#pragma unroll
        for (int j = 0; j < 3; ++j) acc[ti][j] = (f32x4){0.f, 0.f, 0.f, 0.f};

#pragma unroll 1
    for (int kk = 0; kk < 8; ++kk) {
        const int ko = kk * 32;
        float4 sa  = *(const float4*)(stp + ko);
        float4 sb  = *(const float4*)(stp + ko + 4);
        float4 w0a = *(const float4*)(wkp + ko);
        float4 w0b = *(const float4*)(wkp + ko + 4);
        float4 w1a = *(const float4*)(wkp + 256 + ko);
        float4 w1b = *(const float4*)(wkp + 256 + ko + 4);
        float4 w2a = *(const float4*)(wkp + 512 + ko);
        float4 w2b = *(const float4*)(wkp + 512 + ko + 4);
        float4 w3a = *(const float4*)(wkp + 768 + ko);
        float4 w3b = *(const float4*)(wkp + 768 + ko + 4);
        short8 b0 = *(const short8*)(Wt0 + ko);
        short8 b1 = *(const short8*)(Wt0 + 16 * 264 + ko);
        short8 b2 = *(const short8*)(Wt0 + 32 * 264 + ko);
#pragma unroll
        for (int ti = 0; ti < 5; ++ti) {
            const float x0 = xf[ti][0], x1 = xf[ti][1], x2 = xf[ti][2], x3 = xf[ti][3];
            float2 z0 = make_float2(sa.x, sa.y), z1 = make_float2(sa.z, sa.w);
            float2 z2 = make_float2(sb.x, sb.y), z3 = make_float2(sb.z, sb.w);
            z0 = f2fma(x0, make_float2(w0a.x, w0a.y), z0);
            z1 = f2fma(x0, make_float2(w0a.z, w0a.w), z1);
            z2 = f2fma(x0, make_float2(w0b.x, w0b.y), z2);
            z3 = f2fma(x0, make_float2(w0b.z, w0b.w), z3);
            z0 = f2fma(x1, make_float2(w1a.x, w1a.y), z0);
            z1 = f2fma(x1, make_float2(w1a.z, w1a.w), z1);
            z2 = f2fma(x1, make_float2(w1b.x, w1b.y), z2);
            z3 = f2fma(x1, make_float2(w1b.z, w1b.w), z3);
            z0 = f2fma(x2, make_float2(w2a.x, w2a.y), z0);
            z1 = f2fma(x2, make_float2(w2a.z, w2a.w), z1);
            z2 = f2fma(x2, make_float2(w2b.x, w2b.y), z2);
            z3 = f2fma(x2, make_float2(w2b.z, w2b.w), z3);
            z0 = f2fma(x3, make_float2(w3a.x, w3a.y), z0);
            z1 = f2fma(x3, make_float2(w3a.z, w3a.w), z1);
            z2 = f2fma(x3, make_float2(w3b.x, w3b.y), z2);
            z3 = f2fma(x3, make_float2(w3b.z, w3b.w), z3);
            union { short8 s; unsigned int u[4]; } a;
            a.u[0] = packbf2(fast_tanh(z0.x), fast_tanh(z0.y));
            a.u[1] = packbf2(fast_tanh(z1.x), fast_tanh(z1.y));
            a.u[2] = packbf2(fast_tanh(z2.x), fast_tanh(z2.y));
            a.u[3] = packbf2(fast_tanh(z3.x), fast_tanh(z3.y));
            acc[ti][0] = __builtin_amdgcn_mfma_f32_16x16x32_bf16(a.s, b0, acc[ti][0], 0, 0, 0);
            acc[ti][1] = __builtin_amdgcn_mfma_f32_16x16x32_bf16(a.s, b1, acc[ti][1], 0, 0, 0);
            acc[ti][2] = __builtin_amdgcn_mfma_f32_16x16x32_bf16(a.s, b2, acc[ti][2], 0, 0, 0);
        }
    }

    const float bo0 = b_kout[mi], bo1 = b_kout[16 + mi], bo2 = b_kout[32 + mi];
#pragma unroll
    for (int ti = 0; ti < 5; ++ti) {
        const int t = t0 + ti;
#pragma unroll
        for (int reg = 0; reg < 4; ++reg) {
            float km = __expf(acc[ti][0][reg] + bo0);
            float ki = fmaxf(acc[ti][1][reg] + bo1, 0.f);
            float ke = __expf(acc[ti][2][reg] + bo2);
            const int idx = t * 32768 + (s0 + quad * 4 + reg) * 16 + mi;
            kmki[idx] = (unsigned int)f2bf(km) | ((unsigned int)f2bf(ki) << 16);
            keA[idx]  = f2bf(ke);
        }
    }
}

// ---------------- Kernel C v7: one wave PER SITE (2048 waves, 2/SIMD) ----------------
// R7 analysis: 512 waves left half the SIMDs empty and the ~210-cyc/t dependent
// chain fully exposed. Now lanes 16-63 redundantly mirror lanes 0-15 (same site,
// h = lane&15); all loads broadcast-safe; DPP 16-row reduction valid in every row;
// lane 0 stores. 2048 waves -> every SIMD holds 2 waves that interleave latency.
__global__ __launch_bounds__(256, 2) void kC(
    const float* __restrict__ x,
    const unsigned int* __restrict__ kmki, const ushort* __restrict__ keA,
    const float* __restrict__ params, float* __restrict__ yOut)
{
    const int wv = threadIdx.x >> 6, lane = threadIdx.x & 63;
    const int s = blockIdx.x * 4 + wv;      // one site per wave
    const int h = lane & 15;
    const int gid = s * 16 + h;

    const float kp  = params[0 * 32768 + gid];
    const float ksg = params[1 * 32768 + gid];
    const float kd  = params[2 * 32768 + gid];
    const float gd  = params[3 * 32768 + gid];
    const float gl  = params[4 * 32768 + gid];
    const float qbv = params[5 * 32768 + gid];
    const float gi  = params[6 * 32768 + gid];
    const float ge  = params[7 * 32768 + gid];
    float wrga[8];
#pragma unroll
    for (int i = 0; i < 8; ++i) wrga[i] = params[(8 + i) * 32768 + gid];

    float Sf = 0.f, Ss = 0.f, Sg = 0.f;
    float qh[8];
#pragma unroll
    for (int i = 0; i < 8; ++i) qh[i] = 0.f;

    unsigned int a0[8], a1[8]; ushort e0[8], e1[8];
    float2 ab0[8], cd0[8], ab1[8], cd1[8];

#define LOADB(B, tb) do {                                               \
        const int _b = (tb) * 8;                                        \
        _Pragma("unroll")                                               \
        for (int i = 0; i < 8; ++i) {                                   \
            a##B[i] = kmki[(_b + i) * 32768 + gid];                     \
            e##B[i] = keA[(_b + i) * 32768 + gid];                      \
            const int xb = ((_b + i) * 2048 + s) * 6;                   \
            ab##B[i] = *(const float2*)(x + xb);                        \
            cd##B[i] = *(const float2*)(x + xb + 2);                    \
        }                                                               \
    } while (0)

#define COMPUTEB(B, tb) do {                                            \
        float z[8];                                                     \
        _Pragma("unroll")                                               \
        for (int i = 0; i < 8; ++i) {                                   \
            float km = bf2f((ushort)(a##B[i] & 0xffffu));               \
            float ki = bf2f((ushort)(a##B[i] >> 16));                   \
            float ke = bf2f(e##B[i]);                                   \
            float Prcp = ab##B[i].x, ev = ab##B[i].y;                   \
            float T1 = cd##B[i].x, T2 = cd##B[i].y;                     \
            float fl = fminf(fmaxf(T2 * __builtin_amdgcn_rcpf(T2 - T1 + 1e-5f), 0.f), 1.f); \
            float pl = Prcp * fl;                                       \
            float ps = Prcp * (1.f - fl);                               \
            Sf += ps;                                                   \
            float qf = fminf(Sf, km); Sf -= qf;                         \
            float inflow = qf + pl;                                     \
            float qd = inflow * gi;                                     \
            Ss += inflow * (1.f - gi);                                  \
            float E = fminf(fmaxf(Ss, 0.f), ev * ke * ge); Ss -= E;     \
            float qi = fminf(ki, fmaxf(Ss, 0.f)); Ss -= qi;             \
            float qp = kp * fmaxf(Ss - gl, 0.f);                        \
            float qsa = ksg * fminf(fmaxf(Ss, 0.f), gl);                \
            Ss -= qp + qsa;                                             \
            Sg += qsa * gd;                                             \
            float qg = kd * Sg + qbv;                                   \
            Sg *= (1.f - kd);                                           \
            float q = qp + qsa * (1.f - gd) + qg + qd + qi;             \
            qh[i] = q;                                                  \
            float v = 0.f;                                              \
            _Pragma("unroll")                                           \
            for (int k = 0; k < 8; ++k) v = fmaf(wrga[k], qh[(i - k) & 7], v); \
            z[i] = v;                                                   \
        }                                                               \
        _Pragma("unroll")                                               \
        for (int i = 0; i < 8; ++i) z[i] = dpp_add<0xB1>(z[i]);   /* quad_perm xor1 */ \
        _Pragma("unroll")                                               \
        for (int i = 0; i < 8; ++i) z[i] = dpp_add<0x4E>(z[i]);   /* quad_perm xor2 */ \
        _Pragma("unroll")                                               \
        for (int i = 0; i < 8; ++i) z[i] = dpp_add<0x141>(z[i]);  /* row_half_mirror */ \
        _Pragma("unroll")                                               \
        for (int i = 0; i < 8; ++i) z[i] = dpp_add<0x140>(z[i]);  /* row_mirror */ \
        if (lane == 0) {                                                \
            const int tbase = (tb) * 8;                                 \
            _Pragma("unroll")                                           \
            for (int i = 0; i < 8; ++i) {                               \
                const int t = tbase + i;                                \
                if (t >= 7) yOut[(t - 7) * 2048 + s] = z[i];            \
            }                                                           \
        }                                                               \
    } while (0)

    LOADB(0, 0);
    LOADB(1, 1);

    for (int tb2 = 0; tb2 < 63; ++tb2) {
        const int tbA = 2 * tb2;
        COMPUTEB(0, tbA);
        {
            const int pf = (tbA + 2 < 125) ? tbA + 2 : 124;
            LOADB(0, pf);
        }
        const int tbB = 2 * tb2 + 1;
        if (tbB < 125) {
            COMPUTEB(1, tbB);
            const int pf = (tbB + 2 < 125) ? tbB + 2 : 124;
            LOADB(1, pf);
        }
    }
#undef LOADB
#undef COMPUTEB
}

// ---------------- launch ----------------
extern "C" void kernel_launch(void* const* d_in, const int* in_sizes, int n_in,
                              void* d_out, int out_size, void* d_ws, size_t ws_size,
                              hipStream_t stream) {
    const float* x      = (const float*)d_in[0];
    const float* xc     = (const float*)d_in[1];
    const float* W_fc   = (const float*)d_in[2];
    const float* b_fc   = (const float*)d_in[3];
    const float* W_r    = (const float*)d_in[4];
    const float* b_r    = (const float*)d_in[5];
    const float* W_g    = (const float*)d_in[6];
    const float* b_g    = (const float*)d_in[7];
    const float* W_kin  = (const float*)d_in[8];
    const float* b_kin  = (const float*)d_in[9];
    const float* W_kout = (const float*)d_in[10];
    const float* b_kout = (const float*)d_in[11];
    float* yOut = (float*)d_out;

    char* ws = (char*)d_ws;
    float*  stateK = (float*)(ws + 0);                       // 2 MB
    float*  params = (float*)(ws + (2 << 20));               // 2 MB
    ushort* Wt_g   = (ushort*)(ws + (4 << 20));              // 25,344 B (128 KiB reserved)
    unsigned int* kmki = (unsigned int*)(ws + (4 << 20) + (128 << 10)); // 131,072,000 B
    ushort* keA    = (ushort*)(kmki + (size_t)NT * NS * NH);            //  65,536,000 B

    hipLaunchKernelGGL(kA, dim3(2048), dim3(256), 0, stream,
                       xc, W_fc, b_fc, W_r, b_r, W_g, b_g, b_kin, W_kout,
                       stateK, params, Wt_g);
    hipLaunchKernelGGL(kB, dim3(128 * 50), dim3(256), 0, stream,
                       x, stateK, W_kin, b_kout, Wt_g, kmki, keA);
    hipLaunchKernelGGL(kC, dim3(512), dim3(256), 0, stream,
                       x, kmki, keA, params, yOut);
}

// Round 9
// 577.490 us; speedup vs baseline: 1.1263x; 1.1263x over previous
//
#include <hip/hip_runtime.h>
#include <hip/hip_bf16.h>

// Problem constants
#define NT   1000
#define NS   2048
#define NH   16
#define NR   8
#define HS   256
#define TOUT 993   // NT - NR + 1

typedef __attribute__((ext_vector_type(8))) short short8;
typedef __attribute__((ext_vector_type(4))) float f32x4;

__device__ __forceinline__ ushort f2bf(float f) {
    union { float f; unsigned int u; } v; v.f = f;
    unsigned int u = v.u;
    return (ushort)((u + 0x7fffu + ((u >> 16) & 1u)) >> 16);
}
__device__ __forceinline__ float bf2f(ushort u) {
    union { unsigned int i; float f; } v; v.i = ((unsigned int)u) << 16; return v.f;
}
__device__ __forceinline__ unsigned int packbf2(float lo, float hi) {
    union { __hip_bfloat162 b; unsigned int u; } v;
    v.b = __float22bfloat162_rn(make_float2(lo, hi));
    return v.u;
}
__device__ __forceinline__ float sigf(float x) { return 1.f / (1.f + __expf(-x)); }
// tanh via single exp2: tanh(z) = 1 - 2/(exp2(z*2*log2e)+1)
__device__ __forceinline__ float fast_tanh(float z) {
    float e = exp2f(z * 2.885390082f);
    return 1.f - 2.f * __builtin_amdgcn_rcpf(e + 1.f);
}
// paired fma on float2 halves
__device__ __forceinline__ float2 f2fma(float s, float2 w, float2 acc) {
    return make_float2(fmaf(s, w.x, acc.x), fmaf(s, w.y, acc.y));
}
// DPP 16-lane-row reduction step: v += v[dpp-peer]
template<int CTRL>
__device__ __forceinline__ float dpp_add(float v) {
    int s = __builtin_amdgcn_update_dpp(0, __builtin_bit_cast(int, v), CTRL, 0xf, 0xf, true);
    return v + __builtin_bit_cast(float, s);
}

// ---------------- Kernel A: per-site setup (fp32 inputs) ----------------
__global__ __launch_bounds__(256) void kA(
    const float* __restrict__ xc, const float* __restrict__ W_fc, const float* __restrict__ b_fc,
    const float* __restrict__ W_r, const float* __restrict__ b_r,
    const float* __restrict__ W_g, const float* __restrict__ b_g,
    const float* __restrict__ b_kin, const float* __restrict__ W_kout,
    float* __restrict__ stateK, float* __restrict__ params, ushort* __restrict__ Wt_g)
{
    __shared__ float xcs[32];
    __shared__ float hG[256];
    __shared__ float pGR[288];
    const int s = blockIdx.x, tid = threadIdx.x;

    if (tid < 32) xcs[tid] = xc[s * 32 + tid];
    __syncthreads();

    float acc = b_fc[tid];
#pragma unroll 8
    for (int k = 0; k < 32; ++k) acc = fmaf(xcs[k], W_fc[k * 256 + tid], acc);
    stateK[s * 256 + tid] = acc + b_kin[tid];
    hG[tid] = tanhf(acc);
    __syncthreads();

    for (int j = tid; j < 288; j += 256) {
        const float* W = (j < 144) ? W_g : W_r;
        const float* b = (j < 144) ? b_g : b_r;
        int col = (j < 144) ? j : (j - 144);
        float a = b[col];
#pragma unroll 4
        for (int k = 0; k < 256; ++k) a = fmaf(hG[k], W[k * 144 + col], a);
        pGR[j] = a;
    }
    __syncthreads();

    if (tid < 16) {
        const int h = tid;
        float g0 = pGR[h],       g1 = pGR[16 + h],  g2 = pGR[32 + h];
        float g3 = pGR[48 + h],  g4 = pGR[64 + h],  g5 = pGR[80 + h];
        float g6 = pGR[96 + h],  g7 = pGR[112 + h], g8 = pGR[128 + h];
        float kp = sigf(g0), ksg = sigf(g1), kd = sigf(g2), gd = sigf(g3);
        float t4 = sigf(g4) * 10.f; float gl = t4 * t4 * t4;
        float qb = fmaxf(g5, 0.f) * 0.1f;
        float gi = fminf(fmaxf(g7 * (1.f / 6.f) + 0.5f, 0.f), 1.f) * 0.5f;
        float ge = fmaxf(g8, 0.f);
        float m = g6;
        for (int o = 1; o < 16; o <<= 1) m = fmaxf(m, __shfl_xor(m, o));
        float e = __expf(g6 - m), esum = e;
        for (int o = 1; o < 16; o <<= 1) esum += __shfl_xor(esum, o);
        float ga = e / esum;
        float r[9], rm = -1e30f;
#pragma unroll
        for (int i = 0; i < 9; ++i) { r[i] = pGR[144 + h * 9 + i]; rm = fmaxf(rm, r[i]); }
        float er[9], es = 0.f;
#pragma unroll
        for (int i = 0; i < 9; ++i) { er[i] = __expf(r[i] - rm); es += er[i]; }
        float inv_es = 1.f / es, c = 0.f, wsum = 0.f, w[8];
#pragma unroll
        for (int i = 0; i < 8; ++i) {
            float si = er[i] * inv_es; c += si;
            float wi = fminf(c, 1.f - c + si);
            w[i] = wi; wsum += wi;
        }
        const int base = s * 16 + h;
        params[0 * 32768 + base] = kp;  params[1 * 32768 + base] = ksg;
        params[2 * 32768 + base] = kd;  params[3 * 32768 + base] = gd;
        params[4 * 32768 + base] = gl;  params[5 * 32768 + base] = qb;
        params[6 * 32768 + base] = gi;  params[7 * 32768 + base] = ge;
        float sc = ga / wsum;
#pragma unroll
        for (int i = 0; i < 8; ++i) params[(8 + i) * 32768 + base] = w[i] * sc;
    }

    if (s == 0) {
        for (int i = tid; i < 48 * 256; i += 256) {
            int k = i / 48, col = i - k * 48;
            Wt_g[col * 264 + k] = f2bf(W_kout[i]);   // transpose to bf16, stride 264
        }
    }
}

// ---------------- Kernel B v7: like v6 but t-contiguous output layout + met writes ----------------
// New layout: kmki/keA indexed [sg = s>>2][t][sl = s&3][h]  (kC wave = one sg,
// reads 256B/128B contiguous per t, consecutive t adjacent -> sequential streams).
// Quad-0 lanes also emit ps/pl/ev (fp32) in [sg][t][sl] layout.
__global__ __launch_bounds__(256, 3) void kB(
    const float* __restrict__ x,
    const float* __restrict__ stateK, const float* __restrict__ W_kin, const float* __restrict__ b_kout,
    const ushort* __restrict__ Wt_g,
    unsigned int* __restrict__ kmki, ushort* __restrict__ keA,
    float2* __restrict__ pspl, float* __restrict__ evA)
{
    __shared__ ushort Wt[48 * 264];    // 25,344 B
    __shared__ float  stS[16 * 260];   // 16,640 B
    __shared__ float  wkS[1024];       //  4,096 B
    const int tid = threadIdx.x;
    const int st = blockIdx.x & 127;   // site tile (0..127)
    const int tg = blockIdx.x >> 7;    // t group (0..49)
    const int s0 = st << 4;

    for (int i = tid; i < 3168; i += 256)
        ((uint2*)Wt)[i] = ((const uint2*)Wt_g)[i];
#pragma unroll
    for (int i = tid; i < 1024; i += 256) {
        int row = i >> 6, c = (i & 63) << 2;
        *(float4*)(stS + row * 260 + c) = *(const float4*)(stateK + (s0 + row) * 256 + c);
    }
    *(float4*)(wkS + tid * 4) = ((const float4*)W_kin)[tid];
    __syncthreads();

    const int wv = tid >> 6, lane = tid & 63;
    const int mi = lane & 15, quad = lane >> 4;
    const int site = s0 + mi;
    const int t0 = tg * 20 + wv * 5;   // 50*20 = 1000, guard-free

    float xf[5][4];
#pragma unroll
    for (int ti = 0; ti < 5; ++ti) {
        const int t = t0 + ti;
        const int xb = (t * 2048 + site) * 6;
        float2 u23 = *(const float2*)(x + xb + 2);
        float2 u45 = *(const float2*)(x + xb + 4);
        xf[ti][0] = u23.x; xf[ti][1] = u23.y; xf[ti][2] = u45.x; xf[ti][3] = u45.y;
        if (lane < 16) {   // quad 0 emits ps/pl/ev in [sg][t][sl] layout
            float2 u01 = *(const float2*)(x + xb);
            float fl = fminf(fmaxf(u23.y * __builtin_amdgcn_rcpf(u23.y - u23.x + 1e-5f), 0.f), 1.f);
            const int sg = st * 4 + (mi >> 2), sl = mi & 3;
            const int mo = (sg * 1000 + t) * 4 + sl;
            pspl[mo] = make_float2(u01.x * (1.f - fl), u01.x * fl);
            evA[mo]  = u01.y;
        }
    }

    const float* stp = stS + mi * 260 + quad * 8;
    const float* wkp = wkS + quad * 8;
    const ushort* Wt0 = Wt + mi * 264 + quad * 8;

    f32x4 acc[5][3];
#pragma unroll
    for (int ti = 0; ti < 5; ++ti)
#pragma unroll
        for (int j = 0; j < 3; ++j) acc[ti][j] = (f32x4){0.f, 0.f, 0.f, 0.f};

#pragma unroll 1
    for (int kk = 0; kk < 8; ++kk) {
        const int ko = kk * 32;
        float4 sa  = *(const float4*)(stp + ko);
        float4 sb  = *(const float4*)(stp + ko + 4);
        float4 w0a = *(const float4*)(wkp + ko);
        float4 w0b = *(const float4*)(wkp + ko + 4);
        float4 w1a = *(const float4*)(wkp + 256 + ko);
        float4 w1b = *(const float4*)(wkp + 256 + ko + 4);
        float4 w2a = *(const float4*)(wkp + 512 + ko);
        float4 w2b = *(const float4*)(wkp + 512 + ko + 4);
        float4 w3a = *(const float4*)(wkp + 768 + ko);
        float4 w3b = *(const float4*)(wkp + 768 + ko + 4);
        short8 b0 = *(const short8*)(Wt0 + ko);
        short8 b1 = *(const short8*)(Wt0 + 16 * 264 + ko);
        short8 b2 = *(const short8*)(Wt0 + 32 * 264 + ko);
#pragma unroll
        for (int ti = 0; ti < 5; ++ti) {
            const float x0 = xf[ti][0], x1 = xf[ti][1], x2 = xf[ti][2], x3 = xf[ti][3];
            float2 z0 = make_float2(sa.x, sa.y), z1 = make_float2(sa.z, sa.w);
            float2 z2 = make_float2(sb.x, sb.y), z3 = make_float2(sb.z, sb.w);
            z0 = f2fma(x0, make_float2(w0a.x, w0a.y), z0);
            z1 = f2fma(x0, make_float2(w0a.z, w0a.w), z1);
            z2 = f2fma(x0, make_float2(w0b.x, w0b.y), z2);
            z3 = f2fma(x0, make_float2(w0b.z, w0b.w), z3);
            z0 = f2fma(x1, make_float2(w1a.x, w1a.y), z0);
            z1 = f2fma(x1, make_float2(w1a.z, w1a.w), z1);
            z2 = f2fma(x1, make_float2(w1b.x, w1b.y), z2);
            z3 = f2fma(x1, make_float2(w1b.z, w1b.w), z3);
            z0 = f2fma(x2, make_float2(w2a.x, w2a.y), z0);
            z1 = f2fma(x2, make_float2(w2a.z, w2a.w), z1);
            z2 = f2fma(x2, make_float2(w2b.x, w2b.y), z2);
            z3 = f2fma(x2, make_float2(w2b.z, w2b.w), z3);
            z0 = f2fma(x3, make_float2(w3a.x, w3a.y), z0);
            z1 = f2fma(x3, make_float2(w3a.z, w3a.w), z1);
            z2 = f2fma(x3, make_float2(w3b.x, w3b.y), z2);
            z3 = f2fma(x3, make_float2(w3b.z, w3b.w), z3);
            union { short8 s; unsigned int u[4]; } a;
            a.u[0] = packbf2(fast_tanh(z0.x), fast_tanh(z0.y));
            a.u[1] = packbf2(fast_tanh(z1.x), fast_tanh(z1.y));
            a.u[2] = packbf2(fast_tanh(z2.x), fast_tanh(z2.y));
            a.u[3] = packbf2(fast_tanh(z3.x), fast_tanh(z3.y));
            acc[ti][0] = __builtin_amdgcn_mfma_f32_16x16x32_bf16(a.s, b0, acc[ti][0], 0, 0, 0);
            acc[ti][1] = __builtin_amdgcn_mfma_f32_16x16x32_bf16(a.s, b1, acc[ti][1], 0, 0, 0);
            acc[ti][2] = __builtin_amdgcn_mfma_f32_16x16x32_bf16(a.s, b2, acc[ti][2], 0, 0, 0);
        }
    }

    // epilogue: D row = quad*4+reg (site_local), col = mi (head)
    // site = s0 + quad*4 + reg  ->  sg = st*4 + quad, sl = reg
    const float bo0 = b_kout[mi], bo1 = b_kout[16 + mi], bo2 = b_kout[32 + mi];
    const int sgW = st * 4 + quad;
#pragma unroll
    for (int ti = 0; ti < 5; ++ti) {
        const int t = t0 + ti;
#pragma unroll
        for (int reg = 0; reg < 4; ++reg) {
            float km = __expf(acc[ti][0][reg] + bo0);
            float ki = fmaxf(acc[ti][1][reg] + bo1, 0.f);
            float ke = __expf(acc[ti][2][reg] + bo2);
            const int idx = (sgW * 1000 + t) * 64 + (reg << 4) + mi;
            kmki[idx] = (unsigned int)f2bf(km) | ((unsigned int)f2bf(ki) << 16);
            keA[idx]  = f2bf(ke);
        }
    }
}

// ---------------- Kernel C v8: R7 shape + fully t-contiguous streams ----------------
// 512 blocks x 64 threads, one s_group (4 sites) per wave. All reads are
// sequential-in-t streams: kmki 256B/t, keA 128B/t, pspl 32B/t, ev 16B/t.
__global__ __launch_bounds__(64, 1) void kC(
    const unsigned int* __restrict__ kmki, const ushort* __restrict__ keA,
    const float2* __restrict__ pspl, const float* __restrict__ evA,
    const float* __restrict__ params, float* __restrict__ yOut)
{
    const int tid = threadIdx.x;
    const int sg = blockIdx.x;              // s_group, == s>>2 for every lane
    const int s = sg * 4 + (tid >> 4);
    const int h = tid & 15;
    const int gid = s * 16 + h;
    const int sl = tid >> 4;

    const float kp  = params[0 * 32768 + gid];
    const float ksg = params[1 * 32768 + gid];
    const float kd  = params[2 * 32768 + gid];
    const float gd  = params[3 * 32768 + gid];
    const float gl  = params[4 * 32768 + gid];
    const float qbv = params[5 * 32768 + gid];
    const float gi  = params[6 * 32768 + gid];
    const float ge  = params[7 * 32768 + gid];
    float wrga[8];
#pragma unroll
    for (int i = 0; i < 8; ++i) wrga[i] = params[(8 + i) * 32768 + gid];

    float Sf = 0.f, Ss = 0.f, Sg = 0.f;
    float qh[8];
#pragma unroll
    for (int i = 0; i < 8; ++i) qh[i] = 0.f;

    const int base = sg * 1000;

    unsigned int a0[8], a1[8]; ushort e0[8], e1[8];
    float2 p0[8], p1[8]; float v0[8], v1[8];

#define LOADB(B, tb) do {                                               \
        const int _b = base + (tb) * 8;                                 \
        _Pragma("unroll")                                               \
        for (int i = 0; i < 8; ++i) {                                   \
            a##B[i] = kmki[(_b + i) * 64 + tid];                        \
            e##B[i] = keA[(_b + i) * 64 + tid];                         \
            p##B[i] = pspl[(_b + i) * 4 + sl];                          \
            v##B[i] = evA[(_b + i) * 4 + sl];                           \
        }                                                               \
    } while (0)

#define COMPUTEB(B, tb) do {                                            \
        float z[8];                                                     \
        _Pragma("unroll")                                               \
        for (int i = 0; i < 8; ++i) {                                   \
            float km = bf2f((ushort)(a##B[i] & 0xffffu));               \
            float ki = bf2f((ushort)(a##B[i] >> 16));                   \
            float ke = bf2f(e##B[i]);                                   \
            float ps = p##B[i].x, pl = p##B[i].y, ev = v##B[i];         \
            Sf += ps;                                                   \
            float qf = fminf(Sf, km); Sf -= qf;                         \
            float inflow = qf + pl;                                     \
            float qd = inflow * gi;                                     \
            Ss += inflow * (1.f - gi);                                  \
            float E = fminf(fmaxf(Ss, 0.f), ev * ke * ge); Ss -= E;     \
            float qi = fminf(ki, fmaxf(Ss, 0.f)); Ss -= qi;             \
            float qp = kp * fmaxf(Ss - gl, 0.f);                        \
            float qsa = ksg * fminf(fmaxf(Ss, 0.f), gl);                \
            Ss -= qp + qsa;                                             \
            Sg += qsa * gd;                                             \
            float qg = kd * Sg + qbv;                                   \
            Sg *= (1.f - kd);                                           \
            float q = qp + qsa * (1.f - gd) + qg + qd + qi;             \
            qh[i] = q;                                                  \
            float v = 0.f;                                              \
            _Pragma("unroll")                                           \
            for (int k = 0; k < 8; ++k) v = fmaf(wrga[k], qh[(i - k) & 7], v); \
            z[i] = v;                                                   \
        }                                                               \
        _Pragma("unroll")                                               \
        for (int i = 0; i < 8; ++i) z[i] = dpp_add<0xB1>(z[i]);   /* quad_perm xor1 */ \
        _Pragma("unroll")                                               \
        for (int i = 0; i < 8; ++i) z[i] = dpp_add<0x4E>(z[i]);   /* quad_perm xor2 */ \
        _Pragma("unroll")                                               \
        for (int i = 0; i < 8; ++i) z[i] = dpp_add<0x141>(z[i]);  /* row_half_mirror */ \
        _Pragma("unroll")                                               \
        for (int i = 0; i < 8; ++i) z[i] = dpp_add<0x140>(z[i]);  /* row_mirror */ \
        if (h == 0) {                                                   \
            const int tbase = (tb) * 8;                                 \
            _Pragma("unroll")                                           \
            for (int i = 0; i < 8; ++i) {                               \
                const int t = tbase + i;                                \
                if (t >= 7) yOut[(t - 7) * 2048 + s] = z[i];            \
            }                                                           \
        }                                                               \
    } while (0)

    LOADB(0, 0);
    LOADB(1, 1);

    for (int tb2 = 0; tb2 < 63; ++tb2) {
        const int tbA = 2 * tb2;
        COMPUTEB(0, tbA);
        {
            const int pf = (tbA + 2 < 125) ? tbA + 2 : 124;
            LOADB(0, pf);
        }
        const int tbB = 2 * tb2 + 1;
        if (tbB < 125) {
            COMPUTEB(1, tbB);
            const int pf = (tbB + 2 < 125) ? tbB + 2 : 124;
            LOADB(1, pf);
        }
    }
#undef LOADB
#undef COMPUTEB
}

// ---------------- launch ----------------
extern "C" void kernel_launch(void* const* d_in, const int* in_sizes, int n_in,
                              void* d_out, int out_size, void* d_ws, size_t ws_size,
                              hipStream_t stream) {
    const float* x      = (const float*)d_in[0];
    const float* xc     = (const float*)d_in[1];
    const float* W_fc   = (const float*)d_in[2];
    const float* b_fc   = (const float*)d_in[3];
    const float* W_r    = (const float*)d_in[4];
    const float* b_r    = (const float*)d_in[5];
    const float* W_g    = (const float*)d_in[6];
    const float* b_g    = (const float*)d_in[7];
    const float* W_kin  = (const float*)d_in[8];
    const float* b_kin  = (const float*)d_in[9];
    const float* W_kout = (const float*)d_in[10];
    const float* b_kout = (const float*)d_in[11];
    float* yOut = (float*)d_out;

    char* ws = (char*)d_ws;
    float*  stateK = (float*)(ws + 0);                        // 2 MB
    float*  params = (float*)(ws + (2 << 20));                // 2 MB
    ushort* Wt_g   = (ushort*)(ws + (4 << 20));               // 25,344 B (128 KiB reserved)
    char*   p      = ws + (4 << 20) + (128 << 10);
    float2* pspl   = (float2*)p;                              // 512*1000*4*8  = 16,384,000 B
    float*  evA    = (float*)(p + 16384000);                  // 512*1000*4*4  =  8,192,000 B
    unsigned int* kmki = (unsigned int*)(p + 16384000 + 8192000);       // 131,072,000 B
    ushort* keA    = (ushort*)(p + 16384000 + 8192000 + 131072000);     //  65,536,000 B

    hipLaunchKernelGGL(kA, dim3(2048), dim3(256), 0, stream,
                       xc, W_fc, b_fc, W_r, b_r, W_g, b_g, b_kin, W_kout,
                       stateK, params, Wt_g);
    hipLaunchKernelGGL(kB, dim3(128 * 50), dim3(256), 0, stream,
                       x, stateK, W_kin, b_kout, Wt_g, kmki, keA, pspl, evA);
    hipLaunchKernelGGL(kC, dim3(512), dim3(64), 0, stream,
                       kmki, keA, pspl, evA, params, yOut);
}

// Round 10
// 560.885 us; speedup vs baseline: 1.1597x; 1.0296x over previous
//
#include <hip/hip_runtime.h>
#include <hip/hip_bf16.h>

// Problem constants
#define NT   1000
#define NS   2048
#define NH   16
#define NR   8
#define HS   256
#define TOUT 993   // NT - NR + 1

typedef __attribute__((ext_vector_type(8))) short short8;
typedef __attribute__((ext_vector_type(4))) float f32x4;

__device__ __forceinline__ ushort f2bf(float f) {
    union { float f; unsigned int u; } v; v.f = f;
    unsigned int u = v.u;
    return (ushort)((u + 0x7fffu + ((u >> 16) & 1u)) >> 16);
}
__device__ __forceinline__ float bf2f(ushort u) {
    union { unsigned int i; float f; } v; v.i = ((unsigned int)u) << 16; return v.f;
}
__device__ __forceinline__ unsigned int packbf2(float lo, float hi) {
    union { __hip_bfloat162 b; unsigned int u; } v;
    v.b = __float22bfloat162_rn(make_float2(lo, hi));
    return v.u;
}
__device__ __forceinline__ float sigf(float x) { return 1.f / (1.f + __expf(-x)); }
__device__ __forceinline__ float fast_tanh(float z) {
    float e = exp2f(z * 2.885390082f);
    return 1.f - 2.f * __builtin_amdgcn_rcpf(e + 1.f);
}
__device__ __forceinline__ float2 f2fma(float s, float2 w, float2 acc) {
    return make_float2(fmaf(s, w.x, acc.x), fmaf(s, w.y, acc.y));
}
template<int CTRL>
__device__ __forceinline__ float dpp_add(float v) {
    int s = __builtin_amdgcn_update_dpp(0, __builtin_bit_cast(int, v), CTRL, 0xf, 0xf, true);
    return v + __builtin_bit_cast(float, s);
}

// params planes: 0 kp, 1 ks, 2 kd, 3 gd, 4 gl, 5 qb, 6 gi, 7 1-gi, 8 1-kd,
//                9 1-gd, 10 ge, 11..18 wrga
// ---------------- Kernel A: per-site setup ----------------
__global__ __launch_bounds__(256) void kA(
    const float* __restrict__ xc, const float* __restrict__ W_fc, const float* __restrict__ b_fc,
    const float* __restrict__ W_r, const float* __restrict__ b_r,
    const float* __restrict__ W_g, const float* __restrict__ b_g,
    const float* __restrict__ b_kin, const float* __restrict__ W_kout,
    float* __restrict__ stateK, float* __restrict__ params, ushort* __restrict__ Wt_g)
{
    __shared__ float xcs[32];
    __shared__ float hG[256];
    __shared__ float pGR[288];
    const int s = blockIdx.x, tid = threadIdx.x;

    if (tid < 32) xcs[tid] = xc[s * 32 + tid];
    __syncthreads();

    float acc = b_fc[tid];
#pragma unroll 8
    for (int k = 0; k < 32; ++k) acc = fmaf(xcs[k], W_fc[k * 256 + tid], acc);
    stateK[s * 256 + tid] = acc + b_kin[tid];
    hG[tid] = tanhf(acc);
    __syncthreads();

    for (int j = tid; j < 288; j += 256) {
        const float* W = (j < 144) ? W_g : W_r;
        const float* b = (j < 144) ? b_g : b_r;
        int col = (j < 144) ? j : (j - 144);
        float a = b[col];
#pragma unroll 4
        for (int k = 0; k < 256; ++k) a = fmaf(hG[k], W[k * 144 + col], a);
        pGR[j] = a;
    }
    __syncthreads();

    if (tid < 16) {
        const int h = tid;
        float g0 = pGR[h],       g1 = pGR[16 + h],  g2 = pGR[32 + h];
        float g3 = pGR[48 + h],  g4 = pGR[64 + h],  g5 = pGR[80 + h];
        float g6 = pGR[96 + h],  g7 = pGR[112 + h], g8 = pGR[128 + h];
        float kp = sigf(g0), ksg = sigf(g1), kd = sigf(g2), gd = sigf(g3);
        float t4 = sigf(g4) * 10.f; float gl = t4 * t4 * t4;
        float qb = fmaxf(g5, 0.f) * 0.1f;
        float gi = fminf(fmaxf(g7 * (1.f / 6.f) + 0.5f, 0.f), 1.f) * 0.5f;
        float ge = fmaxf(g8, 0.f);
        float m = g6;
        for (int o = 1; o < 16; o <<= 1) m = fmaxf(m, __shfl_xor(m, o));
        float e = __expf(g6 - m), esum = e;
        for (int o = 1; o < 16; o <<= 1) esum += __shfl_xor(esum, o);
        float ga = e / esum;
        float r[9], rm = -1e30f;
#pragma unroll
        for (int i = 0; i < 9; ++i) { r[i] = pGR[144 + h * 9 + i]; rm = fmaxf(rm, r[i]); }
        float er[9], es = 0.f;
#pragma unroll
        for (int i = 0; i < 9; ++i) { er[i] = __expf(r[i] - rm); es += er[i]; }
        float inv_es = 1.f / es, c = 0.f, wsum = 0.f, w[8];
#pragma unroll
        for (int i = 0; i < 8; ++i) {
            float si = er[i] * inv_es; c += si;
            float wi = fminf(c, 1.f - c + si);
            w[i] = wi; wsum += wi;
        }
        const int base = s * 16 + h;
        params[0 * 32768 + base] = kp;       params[1 * 32768 + base] = ksg;
        params[2 * 32768 + base] = kd;       params[3 * 32768 + base] = gd;
        params[4 * 32768 + base] = gl;       params[5 * 32768 + base] = qb;
        params[6 * 32768 + base] = gi;       params[7 * 32768 + base] = 1.f - gi;
        params[8 * 32768 + base] = 1.f - kd; params[9 * 32768 + base] = 1.f - gd;
        params[10 * 32768 + base] = ge;
        float sc = ga / wsum;
#pragma unroll
        for (int i = 0; i < 8; ++i) params[(11 + i) * 32768 + base] = w[i] * sc;
    }

    if (s == 0) {
        for (int i = tid; i < 48 * 256; i += 256) {
            int k = i / 48, col = i - k * 48;
            Wt_g[col * 264 + k] = f2bf(W_kout[i]);   // transpose to bf16, stride 264
        }
    }
}

// ---------------- Kernel B v8: v7 + kev = ke*ev*ge fold (ge/ev via LDS tiles) ----------------
__global__ __launch_bounds__(256, 3) void kB(
    const float* __restrict__ x,
    const float* __restrict__ stateK, const float* __restrict__ W_kin, const float* __restrict__ b_kout,
    const ushort* __restrict__ Wt_g, const float* __restrict__ params,
    unsigned int* __restrict__ kmki, ushort* __restrict__ kevA,
    float2* __restrict__ pspl)
{
    __shared__ ushort Wt[48 * 264];    // 25,344 B
    __shared__ float  stS[16 * 260];   // 16,640 B
    __shared__ float  wkS[1024];       //  4,096 B
    __shared__ float  geS[256];        //  1,024 B  [site_local*16 + h]
    __shared__ float  evS[4][5][16];   //  1,280 B  [wave][ti][site_local]
    const int tid = threadIdx.x;
    const int st = blockIdx.x & 127;   // site tile (0..127)
    const int tg = blockIdx.x >> 7;    // t group (0..49)
    const int s0 = st << 4;

    for (int i = tid; i < 3168; i += 256)
        ((uint2*)Wt)[i] = ((const uint2*)Wt_g)[i];
#pragma unroll
    for (int i = tid; i < 1024; i += 256) {
        int row = i >> 6, c = (i & 63) << 2;
        *(float4*)(stS + row * 260 + c) = *(const float4*)(stateK + (s0 + row) * 256 + c);
    }
    *(float4*)(wkS + tid * 4) = ((const float4*)W_kin)[tid];
    geS[tid] = params[10 * 32768 + s0 * 16 + tid];
    __syncthreads();

    const int wv = tid >> 6, lane = tid & 63;
    const int mi = lane & 15, quad = lane >> 4;
    const int site = s0 + mi;
    const int t0 = tg * 20 + wv * 5;   // 50*20 = 1000, guard-free

    float xf[5][4];
#pragma unroll
    for (int ti = 0; ti < 5; ++ti) {
        const int t = t0 + ti;
        const int xb = (t * 2048 + site) * 6;
        float2 u23 = *(const float2*)(x + xb + 2);
        float2 u45 = *(const float2*)(x + xb + 4);
        xf[ti][0] = u23.x; xf[ti][1] = u23.y; xf[ti][2] = u45.x; xf[ti][3] = u45.y;
        if (lane < 16) {   // quad 0: ps/pl in [sg][t][sl] layout, ev tile in LDS
            float2 u01 = *(const float2*)(x + xb);
            float fl = fminf(fmaxf(u23.y * __builtin_amdgcn_rcpf(u23.y - u23.x + 1e-5f), 0.f), 1.f);
            const int sg = st * 4 + (mi >> 2), sl = mi & 3;
            pspl[(sg * 1000 + t) * 4 + sl] = make_float2(u01.x * (1.f - fl), u01.x * fl);
            evS[wv][ti][mi] = u01.y;
        }
    }

    const float* stp = stS + mi * 260 + quad * 8;
    const float* wkp = wkS + quad * 8;
    const ushort* Wt0 = Wt + mi * 264 + quad * 8;

    f32x4 acc[5][3];
#pragma unroll
    for (int ti = 0; ti < 5; ++ti)
#pragma unroll
        for (int j = 0; j < 3; ++j) acc[ti][j] = (f32x4){0.f, 0.f, 0.f, 0.f};

#pragma unroll 1
    for (int kk = 0; kk < 8; ++kk) {
        const int ko = kk * 32;
        float4 sa  = *(const float4*)(stp + ko);
        float4 sb  = *(const float4*)(stp + ko + 4);
        float4 w0a = *(const float4*)(wkp + ko);
        float4 w0b = *(const float4*)(wkp + ko + 4);
        float4 w1a = *(const float4*)(wkp + 256 + ko);
        float4 w1b = *(const float4*)(wkp + 256 + ko + 4);
        float4 w2a = *(const float4*)(wkp + 512 + ko);
        float4 w2b = *(const float4*)(wkp + 512 + ko + 4);
        float4 w3a = *(const float4*)(wkp + 768 + ko);
        float4 w3b = *(const float4*)(wkp + 768 + ko + 4);
        short8 b0 = *(const short8*)(Wt0 + ko);
        short8 b1 = *(const short8*)(Wt0 + 16 * 264 + ko);
        short8 b2 = *(const short8*)(Wt0 + 32 * 264 + ko);
#pragma unroll
        for (int ti = 0; ti < 5; ++ti) {
            const float x0 = xf[ti][0], x1 = xf[ti][1], x2 = xf[ti][2], x3 = xf[ti][3];
            float2 z0 = make_float2(sa.x, sa.y), z1 = make_float2(sa.z, sa.w);
            float2 z2 = make_float2(sb.x, sb.y), z3 = make_float2(sb.z, sb.w);
            z0 = f2fma(x0, make_float2(w0a.x, w0a.y), z0);
            z1 = f2fma(x0, make_float2(w0a.z, w0a.w), z1);
            z2 = f2fma(x0, make_float2(w0b.x, w0b.y), z2);
            z3 = f2fma(x0, make_float2(w0b.z, w0b.w), z3);
            z0 = f2fma(x1, make_float2(w1a.x, w1a.y), z0);
            z1 = f2fma(x1, make_float2(w1a.z, w1a.w), z1);
            z2 = f2fma(x1, make_float2(w1b.x, w1b.y), z2);
            z3 = f2fma(x1, make_float2(w1b.z, w1b.w), z3);
            z0 = f2fma(x2, make_float2(w2a.x, w2a.y), z0);
            z1 = f2fma(x2, make_float2(w2a.z, w2a.w), z1);
            z2 = f2fma(x2, make_float2(w2b.x, w2b.y), z2);
            z3 = f2fma(x2, make_float2(w2b.z, w2b.w), z3);
            z0 = f2fma(x3, make_float2(w3a.x, w3a.y), z0);
            z1 = f2fma(x3, make_float2(w3a.z, w3a.w), z1);
            z2 = f2fma(x3, make_float2(w3b.x, w3b.y), z2);
            z3 = f2fma(x3, make_float2(w3b.z, w3b.w), z3);
            union { short8 s; unsigned int u[4]; } a;
            a.u[0] = packbf2(fast_tanh(z0.x), fast_tanh(z0.y));
            a.u[1] = packbf2(fast_tanh(z1.x), fast_tanh(z1.y));
            a.u[2] = packbf2(fast_tanh(z2.x), fast_tanh(z2.y));
            a.u[3] = packbf2(fast_tanh(z3.x), fast_tanh(z3.y));
            acc[ti][0] = __builtin_amdgcn_mfma_f32_16x16x32_bf16(a.s, b0, acc[ti][0], 0, 0, 0);
            acc[ti][1] = __builtin_amdgcn_mfma_f32_16x16x32_bf16(a.s, b1, acc[ti][1], 0, 0, 0);
            acc[ti][2] = __builtin_amdgcn_mfma_f32_16x16x32_bf16(a.s, b2, acc[ti][2], 0, 0, 0);
        }
    }

    // epilogue: D row = quad*4+reg (site_local), col = mi (head)
    const float bo0 = b_kout[mi], bo1 = b_kout[16 + mi], bo2 = b_kout[32 + mi];
    const int sgW = st * 4 + quad;
#pragma unroll
    for (int ti = 0; ti < 5; ++ti) {
        const int t = t0 + ti;
#pragma unroll
        for (int reg = 0; reg < 4; ++reg) {
            const int sl = quad * 4 + reg;
            float km = __expf(acc[ti][0][reg] + bo0);
            float ki = fmaxf(acc[ti][1][reg] + bo1, 0.f);
            float ke = __expf(acc[ti][2][reg] + bo2);
            float kev = ke * evS[wv][ti][sl] * geS[sl * 16 + mi];
            const int idx = (sgW * 1000 + t) * 64 + (reg << 4) + mi;
            kmki[idx] = (unsigned int)f2bf(km) | ((unsigned int)f2bf(ki) << 16);
            kevA[idx] = f2bf(kev);
        }
    }
}

// ---------------- Kernel C v9: triple-buffer distance-2, lean scan ----------------
// Streams (per wave per t): kmki 256B, kev 128B, pspl 32B — all t-sequential.
// Ss>=0 invariant lets E=min(Ss,kev), qi=min(ki,Ss), qsa=ks*min(Ss,gl).
__global__ __launch_bounds__(64, 1) void kC(
    const unsigned int* __restrict__ kmki, const ushort* __restrict__ kevA,
    const float2* __restrict__ pspl,
    const float* __restrict__ params, float* __restrict__ yOut)
{
    const int tid = threadIdx.x;
    const int sg = blockIdx.x;              // s_group (4 sites per wave)
    const int sl = tid >> 4;
    const int s = sg * 4 + sl;
    const int h = tid & 15;
    const int gid = s * 16 + h;

    const float kp  = params[0 * 32768 + gid];
    const float ks_ = params[1 * 32768 + gid];
    const float kd  = params[2 * 32768 + gid];
    const float gd  = params[3 * 32768 + gid];
    const float gl  = params[4 * 32768 + gid];
    const float qbv = params[5 * 32768 + gid];
    const float gi  = params[6 * 32768 + gid];
    const float gi1 = params[7 * 32768 + gid];
    const float kd1 = params[8 * 32768 + gid];
    const float gd1 = params[9 * 32768 + gid];
    float wrga[8];
#pragma unroll
    for (int i = 0; i < 8; ++i) wrga[i] = params[(11 + i) * 32768 + gid];

    float Sf = 0.f, Ss = 0.f, Sg = 0.f;
    float qh[8];
#pragma unroll
    for (int i = 0; i < 8; ++i) qh[i] = 0.f;

    const int base = sg * 1000;

    unsigned int a0[8], a1[8], a2[8]; ushort e0[8], e1[8], e2[8];
    float2 p0[8], p1[8], p2[8];

#define LOADB(B, tb) do {                                               \
        const int _b = base + (tb) * 8;                                 \
        _Pragma("unroll")                                               \
        for (int i = 0; i < 8; ++i) {                                   \
            a##B[i] = kmki[(_b + i) * 64 + tid];                        \
            e##B[i] = kevA[(_b + i) * 64 + tid];                        \
            p##B[i] = pspl[(_b + i) * 4 + sl];                          \
        }                                                               \
    } while (0)

#define COMPUTEB(B, tb) do {                                            \
        float z[8];                                                     \
        _Pragma("unroll")                                               \
        for (int i = 0; i < 8; ++i) {                                   \
            float km = __builtin_bit_cast(float, a##B[i] << 16);        \
            float ki = __builtin_bit_cast(float, a##B[i] & 0xffff0000u);\
            float kev = __builtin_bit_cast(float, ((unsigned int)e##B[i]) << 16); \
            float ps = p##B[i].x, pl = p##B[i].y;                       \
            Sf += ps;                                                   \
            float qf = fminf(Sf, km); Sf -= qf;                         \
            float inflow = qf + pl;                                     \
            float qd = inflow * gi;                                     \
            Ss = fmaf(inflow, gi1, Ss);                                 \
            float E = fminf(Ss, kev); Ss -= E;                          \
            float qi = fminf(ki, Ss); Ss -= qi;                         \
            float qp = kp * fmaxf(Ss - gl, 0.f);                        \
            float qsa = ks_ * fminf(Ss, gl);                            \
            Ss -= qp + qsa;                                             \
            Sg = fmaf(qsa, gd, Sg);                                     \
            float qg = fmaf(kd, Sg, qbv);                               \
            Sg *= kd1;                                                  \
            float q = fmaf(qsa, gd1, qp) + qg + qd + qi;                \
            qh[i] = q;                                                  \
            float v = 0.f;                                              \
            _Pragma("unroll")                                           \
            for (int k = 0; k < 8; ++k) v = fmaf(wrga[k], qh[(i - k) & 7], v); \
            z[i] = v;                                                   \
        }                                                               \
        _Pragma("unroll")                                               \
        for (int i = 0; i < 8; ++i) z[i] = dpp_add<0xB1>(z[i]);         \
        _Pragma("unroll")                                               \
        for (int i = 0; i < 8; ++i) z[i] = dpp_add<0x4E>(z[i]);         \
        _Pragma("unroll")                                               \
        for (int i = 0; i < 8; ++i) z[i] = dpp_add<0x141>(z[i]);        \
        _Pragma("unroll")                                               \
        for (int i = 0; i < 8; ++i) z[i] = dpp_add<0x140>(z[i]);        \
        if (h == 0) {                                                   \
            const int tbase = (tb) * 8;                                 \
            _Pragma("unroll")                                           \
            for (int i = 0; i < 8; ++i) {                               \
                const int t = tbase + i;                                \
                if (t >= 7) yOut[(t - 7) * 2048 + s] = z[i];            \
            }                                                           \
        }                                                               \
    } while (0)

    LOADB(0, 0);
    LOADB(1, 1);
    LOADB(2, 2);

    // 125 batches; 42 chunks of 3 (126 slots, last compute guarded).
    for (int it = 0; it < 42; ++it) {
        const int tb = it * 3;
        COMPUTEB(0, tb);
        LOADB(0, (tb + 3 <= 124) ? tb + 3 : 124);
        if (tb + 1 < 125) {
            COMPUTEB(1, tb + 1);
            LOADB(1, (tb + 4 <= 124) ? tb + 4 : 124);
        }
        if (tb + 2 < 125) {
            COMPUTEB(2, tb + 2);
            LOADB(2, (tb + 5 <= 124) ? tb + 5 : 124);
        }
    }
#undef LOADB
#undef COMPUTEB
}

// ---------------- launch ----------------
extern "C" void kernel_launch(void* const* d_in, const int* in_sizes, int n_in,
                              void* d_out, int out_size, void* d_ws, size_t ws_size,
                              hipStream_t stream) {
    const float* x      = (const float*)d_in[0];
    const float* xc     = (const float*)d_in[1];
    const float* W_fc   = (const float*)d_in[2];
    const float* b_fc   = (const float*)d_in[3];
    const float* W_r    = (const float*)d_in[4];
    const float* b_r    = (const float*)d_in[5];
    const float* W_g    = (const float*)d_in[6];
    const float* b_g    = (const float*)d_in[7];
    const float* W_kin  = (const float*)d_in[8];
    const float* b_kin  = (const float*)d_in[9];
    const float* W_kout = (const float*)d_in[10];
    const float* b_kout = (const float*)d_in[11];
    float* yOut = (float*)d_out;

    char* ws = (char*)d_ws;
    float*  stateK = (float*)(ws + 0);                        // 2 MB
    float*  params = (float*)(ws + (2 << 20));                // 19 planes (reserve 4 MB)
    ushort* Wt_g   = (ushort*)(ws + (6 << 20));               // 25,344 B (reserve 128 KiB)
    char*   p      = ws + (6 << 20) + (128 << 10);
    float2* pspl   = (float2*)p;                              // 16,384,000 B
    unsigned int* kmki = (unsigned int*)(p + 16384000);       // 131,072,000 B
    ushort* kevA   = (ushort*)(p + 16384000 + 131072000);     //  65,536,000 B

    hipLaunchKernelGGL(kA, dim3(2048), dim3(256), 0, stream,
                       xc, W_fc, b_fc, W_r, b_r, W_g, b_g, b_kin, W_kout,
                       stateK, params, Wt_g);
    hipLaunchKernelGGL(kB, dim3(128 * 50), dim3(256), 0, stream,
                       x, stateK, W_kin, b_kout, Wt_g, params, kmki, kevA, pspl);
    hipLaunchKernelGGL(kC, dim3(512), dim3(64), 0, stream,
                       kmki, kevA, pspl, params, yOut);
}